// Round 4
// baseline (1562.489 us; speedup 1.0000x reference)
//
#include <hip/hip_runtime.h>
#include <stdint.h>

typedef unsigned long long u64;

#define NVAR 8192
#define NCLS 32768
#define CSEG 16

__device__ __forceinline__ float lane_bc(float v, int l) { return __shfl(v, l); }

__device__ __forceinline__ u64 readfl64(u64 x) {
  unsigned lo = __builtin_amdgcn_readfirstlane((unsigned)x);
  unsigned hi = __builtin_amdgcn_readfirstlane((unsigned)(x >> 32));
  return ((u64)hi << 32) | (u64)lo;
}

// ---------------- kernel 1: vars_fwd = v @ fb0^T  [NVAR,64] ----------------
__global__ __launch_bounds__(256) void k_varsfwd(const float* __restrict__ v,
                                                 const float* __restrict__ fb0,
                                                 float* __restrict__ out) {
  __shared__ float fbt[64 * 64];   // fbt[k][d] = fb0[d][k]
  __shared__ float vrow[4][64];
  int t = threadIdx.x;
#pragma unroll
  for (int i = 0; i < 16; ++i) {
    int idx = i * 256 + t;                       // idx = d*64+k
    fbt[(idx & 63) * 64 + (idx >> 6)] = fb0[idx];
  }
  __syncthreads();
  int w = t >> 6, lane = t & 63;
  for (int rr = 0; rr < 16; rr += 4) {
    int row = blockIdx.x * 16 + rr + w;
    vrow[w][lane] = v[row * 64 + lane];
    __syncthreads();
    double a = 0.0;
#pragma unroll
    for (int k = 0; k < 64; ++k)
      a = fma((double)vrow[w][k], (double)fbt[k * 64 + lane], a);
    out[row * 64 + lane] = (float)a;
    __syncthreads();
  }
}

// ======================= FAST PATH =======================
// pass 1: block = 32 clauses. LDS-staged vfwd gather (no global scattered
// loads). Emits transposed bitmasks (u32 halves) exactly as round 3.
__global__ __launch_bounds__(512, 8) void k_pass1v2(
    const float* __restrict__ pos, const float* __restrict__ neg,
    const float* __restrict__ vfwd, const float* __restrict__ fb1,
    const float* __restrict__ cbias, float* __restrict__ dmat,
    unsigned* __restrict__ vbs32) {
  __shared__ float sbuf[128 * 64];        // 32KB staging; epilogue: fbt+crow
  __shared__ u64 lm[32][4];               // presence masks (64 var-quads)
  __shared__ u64 lsg[32][4];              // sign masks
  int t = threadIdx.x;
  int w = __builtin_amdgcn_readfirstlane(t >> 6);   // warp 0..7
  int lane = t & 63;
  int bx = blockIdx.x;             // 0..1023
  int c0 = bx * 32;                // first clause
  int cb = bx >> 1;                // 64-clause chunk
  int h = bx & 1;                  // which u32 half of the u64 word
  double acc[4];
#pragma unroll
  for (int i = 0; i < 4; ++i) acc[i] = 0.0;

  for (int g = 0; g < 32; ++g) {   // 256-var groups
    // ---- phase 1: stream pos/neg, ballots -> lm/lsg ----
#pragma unroll
    for (int i = 0; i < 4; ++i) {
      int cl = w * 4 + i;
      size_t rb = (size_t)(c0 + cl) * 2048 + (size_t)g * 64 + lane;  // float4
      float4 p = ((const float4*)pos)[rb];
      float4 q = ((const float4*)neg)[rb];
      float sc[4];
      sc[0] = p.x - q.x; sc[1] = p.y - q.y; sc[2] = p.z - q.z; sc[3] = p.w - q.w;
#pragma unroll
      for (int j = 0; j < 4; ++j) {
        u64 m = __ballot(sc[j] != 0.f);
        u64 sg = __ballot(sc[j] < 0.f);
        if (lane == j) { lm[cl][j] = m; lsg[cl][j] = sg; }
      }
    }
    __syncthreads();   // A: masks ready

    // ---- phase 2a: transpose-emit vbs (unchanged from round 3) ----
    {
      int k = w >> 2, j = w & 3;
      u64 row = 0;
      if (lane < 32) row = k ? lsg[lane][j] : lm[lane][j];
      unsigned keep = 0;
#pragma unroll
      for (int vl = 0; vl < 64; ++vl) {
        u64 b = __ballot((row >> vl) & 1);   // bits 0..31 = clauses
        if (lane == vl) keep = (unsigned)b;
      }
      int v = g * 256 + lane * 4 + j;
      vbs32[((size_t)(v * 512 + cb) * 2 + k) * 2 + h] = keep;
    }
    // ---- phase 2b: stage vfwd half 0 (rows g*256 .. +128) ----
    {
      const float4* src = (const float4*)(vfwd + (size_t)g * 256 * 64);
      float4* dst = (float4*)sbuf;
#pragma unroll
      for (int i = 0; i < 4; ++i) dst[t + i * 512] = src[t + i * 512];
    }
    __syncthreads();   // B: half0 staged, transpose done

    // ---- phase 3: gather half 0 (vars l*4+j, l<32) ----
#pragma unroll
    for (int i = 0; i < 4; ++i) {
      int cl = w * 4 + i;
#pragma unroll
      for (int j = 0; j < 4; ++j) {
        u64 m = readfl64(lm[cl][j]) & 0xffffffffULL;
        u64 sg = readfl64(lsg[cl][j]);
        while (m) {
          int l = __builtin_ctzll(m);
          m &= m - 1;
          float dv = sbuf[(l * 4 + j) * 64 + lane];
          acc[i] += ((sg >> l) & 1) ? -(double)dv : (double)dv;
        }
      }
    }
    __syncthreads();   // C: gather0 done, sbuf free

    // ---- phase 4: stage vfwd half 1 (rows g*256+128 .. +256) ----
    {
      const float4* src = (const float4*)(vfwd + ((size_t)g * 256 + 128) * 64);
      float4* dst = (float4*)sbuf;
#pragma unroll
      for (int i = 0; i < 4; ++i) dst[t + i * 512] = src[t + i * 512];
    }
    __syncthreads();   // D: half1 staged

    // ---- phase 5: gather half 1 (vars l*4+j, l>=32) ----
#pragma unroll
    for (int i = 0; i < 4; ++i) {
      int cl = w * 4 + i;
#pragma unroll
      for (int j = 0; j < 4; ++j) {
        u64 m = readfl64(lm[cl][j]) >> 32;
        u64 sg = readfl64(lsg[cl][j]) >> 32;
        while (m) {
          int l = __builtin_ctzll(m);   // orig lane l+32 -> local row l*4+j
          m &= m - 1;
          float dv = sbuf[(l * 4 + j) * 64 + lane];
          acc[i] += ((sg >> l) & 1) ? -(double)dv : (double)dv;
        }
      }
    }
    __syncthreads();   // E: gather1 done; next group may rewrite lm/sbuf
  }

  // ---- epilogue: relu + dmat = c @ fb1^T (sbuf reused: fbt + crow) ----
#pragma unroll
  for (int i2 = 0; i2 < 8; ++i2) {
    int idx = i2 * 512 + t;                      // idx = d*64+k
    sbuf[(idx & 63) * 64 + (idx >> 6)] = fb1[idx];
  }
  float* crow = sbuf + 4096 + w * 64;
  __syncthreads();
  for (int i = 0; i < 4; ++i) {
    float cv = fmaxf((float)acc[i] + cbias[lane], 0.f);
    crow[lane] = cv;
    __syncthreads();
    double da = 0.0;
#pragma unroll
    for (int k = 0; k < 64; ++k)
      da = fma((double)crow[k], (double)sbuf[k * 64 + lane], da);
    dmat[(size_t)(c0 + w * 4 + i) * 64 + lane] = (float)da;
    __syncthreads();
  }
}

// pass 2: per-variable gather, 8 mask words in flight (MLP ~4-8).
__global__ __launch_bounds__(256, 8) void k_gather2(const u64* __restrict__ vbs,
                                                    const float* __restrict__ dmat,
                                                    float* __restrict__ nv) {
  int w = __builtin_amdgcn_readfirstlane(threadIdx.x >> 6);
  int lane = threadIdx.x & 63;
  int v = blockIdx.x * 4 + w;
  const u64* p = vbs + (size_t)v * 1024;   // 512 x {m, s}
  double acc = 0.0;
  for (int cc = 0; cc < 512; cc += 8) {
    u64 m[8], s[8];
#pragma unroll
    for (int q = 0; q < 8; ++q) {
      m[q] = readfl64(p[(cc + q) * 2]);
      s[q] = readfl64(p[(cc + q) * 2 + 1]);
    }
    while (m[0] | m[1] | m[2] | m[3] | m[4] | m[5] | m[6] | m[7]) {
      float dv[8];
      int sgn[8];
      bool has[8];
#pragma unroll
      for (int q = 0; q < 8; ++q) {
        has[q] = (m[q] != 0);
        if (has[q]) {
          int l = __builtin_ctzll(m[q]);
          m[q] &= m[q] - 1;
          sgn[q] = (int)((s[q] >> l) & 1);
          dv[q] = dmat[(((size_t)(cc + q) << 6) + l) * 64 + lane];
        }
      }
#pragma unroll
      for (int q = 0; q < 8; ++q)
        if (has[q]) acc += sgn[q] ? -(double)dv[q] : (double)dv[q];
    }
  }
  nv[(size_t)v * 64 + lane] = (float)acc;
}

// ======================= FALLBACK PATH (ws too small) =======================
__global__ __launch_bounds__(256) void k_pass1_basic(
    const float* __restrict__ pos, const float* __restrict__ neg,
    const float* __restrict__ bmat, const float* __restrict__ fb1,
    const float* __restrict__ cbias, float* __restrict__ dmat) {
  __shared__ float fbt[64 * 64];
  __shared__ float crow[4][64];
  int t = threadIdx.x;
#pragma unroll
  for (int i = 0; i < 16; ++i) {
    int idx = i * 256 + t;
    fbt[(idx & 63) * 64 + (idx >> 6)] = fb1[idx];
  }
  __syncthreads();
  int w = t >> 6, lane = t & 63;
  int c = blockIdx.x * 4 + w;
  const float4* prow = (const float4*)(pos + (size_t)c * NVAR);
  const float4* nrow = (const float4*)(neg + (size_t)c * NVAR);
  double acc = 0.0;
  for (int g = 0; g < 32; ++g) {
    float4 p = prow[g * 64 + lane];
    float4 q = nrow[g * 64 + lane];
    float sc[4];
    sc[0] = p.x - q.x; sc[1] = p.y - q.y; sc[2] = p.z - q.z; sc[3] = p.w - q.w;
#pragma unroll
    for (int j = 0; j < 4; ++j) {
      float s = sc[j];
      u64 m = __ballot(s != 0.f);
      u64 sg = __ballot(s < 0.f);
      while (m) {
        int l = __builtin_ctzll(m);
        m &= m - 1;
        float dv = bmat[(size_t)((g << 8) + (l << 2) + j) * 64 + lane];
        acc += ((sg >> l) & 1) ? -(double)dv : (double)dv;
      }
    }
  }
  float cv = fmaxf((float)acc + cbias[lane], 0.f);
  crow[w][lane] = cv;
  __syncthreads();
  double da = 0.0;
#pragma unroll
  for (int k = 0; k < 64; ++k)
    da = fma((double)crow[w][k], (double)fbt[k * 64 + lane], da);
  dmat[(size_t)c * 64 + lane] = (float)da;
}

__global__ __launch_bounds__(256) void k_pass2_dense(
    const float* __restrict__ pos, const float* __restrict__ neg,
    const float* __restrict__ dmat, float* __restrict__ nv) {
  __shared__ float acc[64 * 64];
  int t = threadIdx.x;
#pragma unroll
  for (int i = 0; i < 16; ++i) acc[i * 256 + t] = 0.f;
  __syncthreads();
  int w = t >> 6, lane = t & 63;
  int s = blockIdx.x / CSEG, seg = blockIdx.x % CSEG;
  int c0 = seg * (NCLS / CSEG);
  for (int c = c0 + w; c < c0 + NCLS / CSEG; c += 4) {
    float p = pos[(size_t)c * NVAR + (s << 6) + lane];
    float q = neg[(size_t)c * NVAR + (s << 6) + lane];
    float sv = p - q;
    u64 m = __ballot(sv != 0.f);
    if (!m) continue;
    float dv = dmat[(size_t)c * 64 + lane];
    while (m) {
      int l = __builtin_ctzll(m);
      m &= m - 1;
      float sl = lane_bc(sv, l);
      atomicAdd(&acc[(l << 6) + lane], sl * dv);
    }
  }
  __syncthreads();
  size_t obase = (size_t)s * 4096;
#pragma unroll
  for (int i = 0; i < 16; ++i) {
    int idx = i * 256 + t;
    atomicAdd(&nv[obase + idx], acc[idx]);
  }
}

// ------- tail 1: ve2 = tanh(cat(ground, relu(nv+vb)) @ Wg^T + bg) -------
__global__ __launch_bounds__(256) void k_tail1(
    const float* __restrict__ nv, const float* __restrict__ vb,
    const float* __restrict__ ground, const float* __restrict__ Wg,
    const float* __restrict__ bg, float* __restrict__ ve2out) {
  __shared__ float wt[72 * 64];   // wt[k][d] = Wg[d][k]
  __shared__ float inrow[4][72];
  int t = threadIdx.x;
#pragma unroll
  for (int i = 0; i < 18; ++i) {
    int idx = i * 256 + t;                       // d*72+k
    wt[(idx % 72) * 64 + (idx / 72)] = Wg[idx];
  }
  __syncthreads();
  int w = t >> 6, lane = t & 63;
  for (int rr = 0; rr < 32; rr += 4) {
    int row = blockIdx.x * 32 + rr + w;
    float ve = fmaxf(nv[row * 64 + lane] + vb[lane], 0.f);
    inrow[w][8 + lane] = ve;
    if (lane < 8) inrow[w][lane] = ground[row * 8 + lane];
    __syncthreads();
    double a = 0.0;
#pragma unroll
    for (int k = 0; k < 72; ++k)
      a = fma((double)inrow[w][k], (double)wt[k * 64 + lane], a);
    ve2out[row * 64 + lane] = tanhf((float)a + bg[lane]);
    __syncthreads();
  }
}

// ------- tail GRU: M=0 -> z, M=1 -> rp=r*prev, M=2 -> h & final output -------
template <int M>
__global__ __launch_bounds__(256) void k_tailg(
    const float* __restrict__ ve2, const float* __restrict__ in2,
    const float* __restrict__ W, const float* __restrict__ U,
    const float* __restrict__ bias, const float* __restrict__ prev,
    const float* __restrict__ zbuf, float* __restrict__ outbuf) {
  __shared__ float wt[64 * 64], ut[64 * 64];
  __shared__ float xr[4][64], yr[4][64];
  int t = threadIdx.x;
#pragma unroll
  for (int i = 0; i < 16; ++i) {
    int idx = i * 256 + t;
    wt[(idx & 63) * 64 + (idx >> 6)] = W[idx];
    ut[(idx & 63) * 64 + (idx >> 6)] = U[idx];
  }
  __syncthreads();
  int w = t >> 6, lane = t & 63;
  for (int rr = 0; rr < 32; rr += 4) {
    int row = blockIdx.x * 32 + rr + w;
    xr[w][lane] = ve2[row * 64 + lane];
    yr[w][lane] = in2[row * 64 + lane];
    __syncthreads();
    float a = bias[lane];
#pragma unroll
    for (int k = 0; k < 64; ++k) a = fmaf(xr[w][k], wt[k * 64 + lane], a);
#pragma unroll
    for (int k = 0; k < 64; ++k) a = fmaf(yr[w][k], ut[k * 64 + lane], a);
    float res;
    if (M == 0) {
      res = 1.f / (1.f + expf(-a));
    } else if (M == 1) {
      float r = 1.f / (1.f + expf(-a));
      res = r * prev[row * 64 + lane];
    } else {
      float h = tanhf(a);
      float z = zbuf[row * 64 + lane];
      float p = prev[row * 64 + lane];
      res = (1.f - z) * p + z * h;
    }
    outbuf[row * 64 + lane] = res;
    __syncthreads();
  }
}

extern "C" void kernel_launch(void* const* d_in, const int* in_sizes, int n_in,
                              void* d_out, int out_size, void* d_ws, size_t ws_size,
                              hipStream_t stream) {
  const float* variables = (const float*)d_in[0];
  const float* ground    = (const float*)d_in[1];
  const float* cpos      = (const float*)d_in[2];
  const float* cneg      = (const float*)d_in[3];
  const float* fb        = (const float*)d_in[6];
  const float* vb        = (const float*)d_in[7];
  const float* cb        = (const float*)d_in[8];
  const float* Wg        = (const float*)d_in[9];
  const float* bg        = (const float*)d_in[10];
  const float* Wz        = (const float*)d_in[11];
  const float* Uz        = (const float*)d_in[12];
  const float* bz        = (const float*)d_in[13];
  const float* Wr        = (const float*)d_in[14];
  const float* Ur        = (const float*)d_in[15];
  const float* br        = (const float*)d_in[16];
  const float* Wh        = (const float*)d_in[17];
  const float* Uh        = (const float*)d_in[18];
  const float* bh        = (const float*)d_in[19];
  float* out = (float*)d_out;
  char* ws = (char*)d_ws;
  const size_t MB = (size_t)1 << 20;

  float* vfwd  = (float*)(ws + 0);        // 2 MB (later reused as ve2)
  float* dmat  = (float*)(ws + 2 * MB);   // 8 MB
  float* nv    = (float*)(ws + 10 * MB);  // 2 MB
  float* zbuf  = (float*)(ws + 12 * MB);  // 2 MB
  float* rpbuf = (float*)(ws + 14 * MB);  // 2 MB
  u64* vbs     = (u64*)(ws + 16 * MB);    // 64 MB: [var][512][2] {mask, sign}
  bool fast = ws_size >= 80 * MB;

  k_varsfwd<<<512, 256, 0, stream>>>(variables, fb, vfwd);
  if (fast) {
    k_pass1v2<<<1024, 512, 0, stream>>>(cpos, cneg, vfwd, fb + 4096, cb, dmat,
                                        (unsigned*)vbs);
    k_gather2<<<2048, 256, 0, stream>>>(vbs, dmat, nv);
  } else {
    k_pass1_basic<<<8192, 256, 0, stream>>>(cpos, cneg, vfwd, fb + 4096, cb, dmat);
    hipMemsetAsync(nv, 0, (size_t)NVAR * 64 * sizeof(float), stream);
    k_pass2_dense<<<128 * CSEG, 256, 0, stream>>>(cpos, cneg, dmat, nv);
  }
  k_tail1<<<256, 256, 0, stream>>>(nv, vb, ground, Wg, bg, vfwd);
  k_tailg<0><<<256, 256, 0, stream>>>(vfwd, variables, Wz, Uz, bz, variables,
                                      nullptr, zbuf);
  k_tailg<1><<<256, 256, 0, stream>>>(vfwd, variables, Wr, Ur, br, variables,
                                      nullptr, rpbuf);
  k_tailg<2><<<256, 256, 0, stream>>>(vfwd, rpbuf, Wh, Uh, bh, variables, zbuf,
                                      out);
}

// Round 5
// 1203.567 us; speedup vs baseline: 1.2982x; 1.2982x over previous
//
#include <hip/hip_runtime.h>
#include <stdint.h>

typedef unsigned long long u64;

#define NVAR 8192
#define NCLS 32768
#define CSEG 16
#define GSEG 4           // gather segments (128 chunks each)

__device__ __forceinline__ float lane_bc(float v, int l) { return __shfl(v, l); }

__device__ __forceinline__ u64 readfl64(u64 x) {
  unsigned lo = __builtin_amdgcn_readfirstlane((unsigned)x);
  unsigned hi = __builtin_amdgcn_readfirstlane((unsigned)(x >> 32));
  return ((u64)hi << 32) | (u64)lo;
}

// ---------------- kernel 1: vars_fwd = v @ fb0^T  [NVAR,64] ----------------
__global__ __launch_bounds__(256) void k_varsfwd(const float* __restrict__ v,
                                                 const float* __restrict__ fb0,
                                                 float* __restrict__ out) {
  __shared__ float fbt[64 * 64];   // fbt[k][d] = fb0[d][k]
  __shared__ float vrow[4][64];
  int t = threadIdx.x;
#pragma unroll
  for (int i = 0; i < 16; ++i) {
    int idx = i * 256 + t;                       // idx = d*64+k
    fbt[(idx & 63) * 64 + (idx >> 6)] = fb0[idx];
  }
  __syncthreads();
  int w = t >> 6, lane = t & 63;
  for (int rr = 0; rr < 16; rr += 4) {
    int row = blockIdx.x * 16 + rr + w;
    vrow[w][lane] = v[row * 64 + lane];
    __syncthreads();
    double a = 0.0;
#pragma unroll
    for (int k = 0; k < 64; ++k)
      a = fma((double)vrow[w][k], (double)fbt[k * 64 + lane], a);
    out[row * 64 + lane] = (float)a;
    __syncthreads();
  }
}

// ======================= FAST PATH =======================
// pass 1: block = 32 clauses. LDS-staged vfwd gather; 2-deep global prefetch
// in the ballot phase. Emits transposed bitmasks (u32 halves).
__global__ __launch_bounds__(512, 8) void k_pass1v2(
    const float* __restrict__ pos, const float* __restrict__ neg,
    const float* __restrict__ vfwd, const float* __restrict__ fb1,
    const float* __restrict__ cbias, float* __restrict__ dmat,
    unsigned* __restrict__ vbs32) {
  __shared__ float sbuf[128 * 64];        // 32KB staging; epilogue: fbt+crow
  __shared__ u64 lm[32][4];               // presence masks
  __shared__ u64 lsg[32][4];              // sign masks
  int t = threadIdx.x;
  int w = __builtin_amdgcn_readfirstlane(t >> 6);   // warp 0..7
  int lane = t & 63;
  int bx = blockIdx.x;             // 0..1023
  int c0 = bx * 32;                // first clause
  int cb = bx >> 1;                // 64-clause chunk
  int h = bx & 1;                  // which u32 half of the u64 word
  double acc[4];
#pragma unroll
  for (int i = 0; i < 4; ++i) acc[i] = 0.0;

  for (int g = 0; g < 32; ++g) {   // 256-var groups
    // ---- phase 1: stream pos/neg (2 clause-pairs in flight), ballots ----
#pragma unroll
    for (int i = 0; i < 4; i += 2) {
      size_t rb0 = (size_t)(c0 + w * 4 + i) * 2048 + (size_t)g * 64 + lane;
      size_t rb1 = rb0 + 2048;
      float4 p0 = ((const float4*)pos)[rb0];
      float4 q0 = ((const float4*)neg)[rb0];
      float4 p1 = ((const float4*)pos)[rb1];
      float4 q1 = ((const float4*)neg)[rb1];
      float s0[4], s1[4];
      s0[0] = p0.x - q0.x; s0[1] = p0.y - q0.y; s0[2] = p0.z - q0.z; s0[3] = p0.w - q0.w;
      s1[0] = p1.x - q1.x; s1[1] = p1.y - q1.y; s1[2] = p1.z - q1.z; s1[3] = p1.w - q1.w;
      int cl0 = w * 4 + i, cl1 = cl0 + 1;
#pragma unroll
      for (int j = 0; j < 4; ++j) {
        u64 m = __ballot(s0[j] != 0.f);
        u64 sg = __ballot(s0[j] < 0.f);
        if (lane == j) { lm[cl0][j] = m; lsg[cl0][j] = sg; }
      }
#pragma unroll
      for (int j = 0; j < 4; ++j) {
        u64 m = __ballot(s1[j] != 0.f);
        u64 sg = __ballot(s1[j] < 0.f);
        if (lane == j) { lm[cl1][j] = m; lsg[cl1][j] = sg; }
      }
    }
    __syncthreads();   // A: masks ready

    // ---- phase 2a: transpose-emit vbs ----
    {
      int k = w >> 2, j = w & 3;
      u64 row = 0;
      if (lane < 32) row = k ? lsg[lane][j] : lm[lane][j];
      unsigned keep = 0;
#pragma unroll
      for (int vl = 0; vl < 64; ++vl) {
        u64 b = __ballot((row >> vl) & 1);   // bits 0..31 = clauses
        if (lane == vl) keep = (unsigned)b;
      }
      int v = g * 256 + lane * 4 + j;
      vbs32[((size_t)(v * 512 + cb) * 2 + k) * 2 + h] = keep;
    }
    // ---- phase 2b: stage vfwd half 0 (rows g*256 .. +128) ----
    {
      const float4* src = (const float4*)(vfwd + (size_t)g * 256 * 64);
      float4* dst = (float4*)sbuf;
#pragma unroll
      for (int i = 0; i < 4; ++i) dst[t + i * 512] = src[t + i * 512];
    }
    __syncthreads();   // B: half0 staged, transpose done

    // ---- phase 3: gather half 0 ----
#pragma unroll
    for (int i = 0; i < 4; ++i) {
      int cl = w * 4 + i;
#pragma unroll
      for (int j = 0; j < 4; ++j) {
        u64 m = readfl64(lm[cl][j]) & 0xffffffffULL;
        u64 sg = readfl64(lsg[cl][j]);
        while (m) {
          int l = __builtin_ctzll(m);
          m &= m - 1;
          float dv = sbuf[(l * 4 + j) * 64 + lane];
          acc[i] += ((sg >> l) & 1) ? -(double)dv : (double)dv;
        }
      }
    }
    __syncthreads();   // C: gather0 done, sbuf free

    // ---- phase 4: stage vfwd half 1 ----
    {
      const float4* src = (const float4*)(vfwd + ((size_t)g * 256 + 128) * 64);
      float4* dst = (float4*)sbuf;
#pragma unroll
      for (int i = 0; i < 4; ++i) dst[t + i * 512] = src[t + i * 512];
    }
    __syncthreads();   // D: half1 staged

    // ---- phase 5: gather half 1 ----
#pragma unroll
    for (int i = 0; i < 4; ++i) {
      int cl = w * 4 + i;
#pragma unroll
      for (int j = 0; j < 4; ++j) {
        u64 m = readfl64(lm[cl][j]) >> 32;
        u64 sg = readfl64(lsg[cl][j]) >> 32;
        while (m) {
          int l = __builtin_ctzll(m);
          m &= m - 1;
          float dv = sbuf[(l * 4 + j) * 64 + lane];
          acc[i] += ((sg >> l) & 1) ? -(double)dv : (double)dv;
        }
      }
    }
    __syncthreads();   // E: gather1 done
  }

  // ---- epilogue: relu + dmat = c @ fb1^T (sbuf reused: fbt + crow) ----
#pragma unroll
  for (int i2 = 0; i2 < 8; ++i2) {
    int idx = i2 * 512 + t;                      // idx = d*64+k
    sbuf[(idx & 63) * 64 + (idx >> 6)] = fb1[idx];
  }
  float* crow = sbuf + 4096 + w * 64;
  __syncthreads();
  for (int i = 0; i < 4; ++i) {
    float cv = fmaxf((float)acc[i] + cbias[lane], 0.f);
    crow[lane] = cv;
    __syncthreads();
    double da = 0.0;
#pragma unroll
    for (int k = 0; k < 64; ++k)
      da = fma((double)crow[k], (double)sbuf[k * 64 + lane], da);
    dmat[(size_t)(c0 + w * 4 + i) * 64 + lane] = (float)da;
    __syncthreads();
  }
}

// pass 2: segmented per-variable gather (round-3 inner structure).
// grid = GSEG * 2048, seg-major so co-resident blocks share a 2MB dmat slice.
__global__ __launch_bounds__(256, 8) void k_gather3(const u64* __restrict__ vbs,
                                                    const float* __restrict__ dmat,
                                                    double* __restrict__ nvd) {
  int w = __builtin_amdgcn_readfirstlane(threadIdx.x >> 6);
  int lane = threadIdx.x & 63;
  int seg = blockIdx.x >> 11;              // 0..GSEG-1 (changes slowest)
  int v = (blockIdx.x & 2047) * 4 + w;
  const u64* p = vbs + (size_t)v * 1024;   // 512 x {m, s}
  int cc0 = seg * (512 / GSEG);
  double acc = 0.0;
  for (int cc4 = cc0; cc4 < cc0 + 512 / GSEG; cc4 += 4) {
    u64 mm[4], ss[4];
#pragma unroll
    for (int q = 0; q < 4; ++q) {
      mm[q] = p[(cc4 + q) * 2];
      ss[q] = p[(cc4 + q) * 2 + 1];
    }
#pragma unroll
    for (int q = 0; q < 4; ++q) {
      u64 m = mm[q];
      u64 s = ss[q];
      size_t cbase = (size_t)(cc4 + q) << 12;   // (cc*64)*64 floats
      while (m) {
        int l = __builtin_ctzll(m);
        m &= m - 1;
        float dv = dmat[cbase + ((size_t)l << 6) + lane];
        acc += ((s >> l) & 1) ? -(double)dv : (double)dv;
      }
    }
  }
  atomicAdd(&nvd[(size_t)v * 64 + lane], acc);
}

// ======================= FALLBACK PATH (ws too small) =======================
__global__ __launch_bounds__(256) void k_pass1_basic(
    const float* __restrict__ pos, const float* __restrict__ neg,
    const float* __restrict__ bmat, const float* __restrict__ fb1,
    const float* __restrict__ cbias, float* __restrict__ dmat) {
  __shared__ float fbt[64 * 64];
  __shared__ float crow[4][64];
  int t = threadIdx.x;
#pragma unroll
  for (int i = 0; i < 16; ++i) {
    int idx = i * 256 + t;
    fbt[(idx & 63) * 64 + (idx >> 6)] = fb1[idx];
  }
  __syncthreads();
  int w = t >> 6, lane = t & 63;
  int c = blockIdx.x * 4 + w;
  const float4* prow = (const float4*)(pos + (size_t)c * NVAR);
  const float4* nrow = (const float4*)(neg + (size_t)c * NVAR);
  double acc = 0.0;
  for (int g = 0; g < 32; ++g) {
    float4 p = prow[g * 64 + lane];
    float4 q = nrow[g * 64 + lane];
    float sc[4];
    sc[0] = p.x - q.x; sc[1] = p.y - q.y; sc[2] = p.z - q.z; sc[3] = p.w - q.w;
#pragma unroll
    for (int j = 0; j < 4; ++j) {
      float s = sc[j];
      u64 m = __ballot(s != 0.f);
      u64 sg = __ballot(s < 0.f);
      while (m) {
        int l = __builtin_ctzll(m);
        m &= m - 1;
        float dv = bmat[(size_t)((g << 8) + (l << 2) + j) * 64 + lane];
        acc += ((sg >> l) & 1) ? -(double)dv : (double)dv;
      }
    }
  }
  float cv = fmaxf((float)acc + cbias[lane], 0.f);
  crow[w][lane] = cv;
  __syncthreads();
  double da = 0.0;
#pragma unroll
  for (int k = 0; k < 64; ++k)
    da = fma((double)crow[w][k], (double)fbt[k * 64 + lane], da);
  dmat[(size_t)c * 64 + lane] = (float)da;
}

__global__ __launch_bounds__(256) void k_pass2_dense(
    const float* __restrict__ pos, const float* __restrict__ neg,
    const float* __restrict__ dmat, double* __restrict__ nvd) {
  __shared__ float acc[64 * 64];
  int t = threadIdx.x;
#pragma unroll
  for (int i = 0; i < 16; ++i) acc[i * 256 + t] = 0.f;
  __syncthreads();
  int w = t >> 6, lane = t & 63;
  int s = blockIdx.x / CSEG, seg = blockIdx.x % CSEG;
  int c0 = seg * (NCLS / CSEG);
  for (int c = c0 + w; c < c0 + NCLS / CSEG; c += 4) {
    float p = pos[(size_t)c * NVAR + (s << 6) + lane];
    float q = neg[(size_t)c * NVAR + (s << 6) + lane];
    float sv = p - q;
    u64 m = __ballot(sv != 0.f);
    if (!m) continue;
    float dv = dmat[(size_t)c * 64 + lane];
    while (m) {
      int l = __builtin_ctzll(m);
      m &= m - 1;
      float sl = lane_bc(sv, l);
      atomicAdd(&acc[(l << 6) + lane], sl * dv);
    }
  }
  __syncthreads();
  size_t obase = (size_t)s * 4096;
#pragma unroll
  for (int i = 0; i < 16; ++i) {
    int idx = i * 256 + t;
    atomicAdd(&nvd[obase + idx], (double)acc[idx]);
  }
}

// ------- tail 1: ve2 = tanh(cat(ground, relu(nvd+vb)) @ Wg^T + bg) -------
__global__ __launch_bounds__(256) void k_tail1(
    const double* __restrict__ nvd, const float* __restrict__ vb,
    const float* __restrict__ ground, const float* __restrict__ Wg,
    const float* __restrict__ bg, float* __restrict__ ve2out) {
  __shared__ float wt[72 * 64];   // wt[k][d] = Wg[d][k]
  __shared__ float inrow[4][72];
  int t = threadIdx.x;
#pragma unroll
  for (int i = 0; i < 18; ++i) {
    int idx = i * 256 + t;                       // d*72+k
    wt[(idx % 72) * 64 + (idx / 72)] = Wg[idx];
  }
  __syncthreads();
  int w = t >> 6, lane = t & 63;
  for (int rr = 0; rr < 32; rr += 4) {
    int row = blockIdx.x * 32 + rr + w;
    float ve = fmaxf((float)nvd[row * 64 + lane] + vb[lane], 0.f);
    inrow[w][8 + lane] = ve;
    if (lane < 8) inrow[w][lane] = ground[row * 8 + lane];
    __syncthreads();
    double a = 0.0;
#pragma unroll
    for (int k = 0; k < 72; ++k)
      a = fma((double)inrow[w][k], (double)wt[k * 64 + lane], a);
    ve2out[row * 64 + lane] = tanhf((float)a + bg[lane]);
    __syncthreads();
  }
}

// ------- tail GRU: M=0 -> z, M=1 -> rp=r*prev, M=2 -> h & final output -------
template <int M>
__global__ __launch_bounds__(256) void k_tailg(
    const float* __restrict__ ve2, const float* __restrict__ in2,
    const float* __restrict__ W, const float* __restrict__ U,
    const float* __restrict__ bias, const float* __restrict__ prev,
    const float* __restrict__ zbuf, float* __restrict__ outbuf) {
  __shared__ float wt[64 * 64], ut[64 * 64];
  __shared__ float xr[4][64], yr[4][64];
  int t = threadIdx.x;
#pragma unroll
  for (int i = 0; i < 16; ++i) {
    int idx = i * 256 + t;
    wt[(idx & 63) * 64 + (idx >> 6)] = W[idx];
    ut[(idx & 63) * 64 + (idx >> 6)] = U[idx];
  }
  __syncthreads();
  int w = t >> 6, lane = t & 63;
  for (int rr = 0; rr < 32; rr += 4) {
    int row = blockIdx.x * 32 + rr + w;
    xr[w][lane] = ve2[row * 64 + lane];
    yr[w][lane] = in2[row * 64 + lane];
    __syncthreads();
    float a = bias[lane];
#pragma unroll
    for (int k = 0; k < 64; ++k) a = fmaf(xr[w][k], wt[k * 64 + lane], a);
#pragma unroll
    for (int k = 0; k < 64; ++k) a = fmaf(yr[w][k], ut[k * 64 + lane], a);
    float res;
    if (M == 0) {
      res = 1.f / (1.f + expf(-a));
    } else if (M == 1) {
      float r = 1.f / (1.f + expf(-a));
      res = r * prev[row * 64 + lane];
    } else {
      float h = tanhf(a);
      float z = zbuf[row * 64 + lane];
      float p = prev[row * 64 + lane];
      res = (1.f - z) * p + z * h;
    }
    outbuf[row * 64 + lane] = res;
    __syncthreads();
  }
}

extern "C" void kernel_launch(void* const* d_in, const int* in_sizes, int n_in,
                              void* d_out, int out_size, void* d_ws, size_t ws_size,
                              hipStream_t stream) {
  const float* variables = (const float*)d_in[0];
  const float* ground    = (const float*)d_in[1];
  const float* cpos      = (const float*)d_in[2];
  const float* cneg      = (const float*)d_in[3];
  const float* fb        = (const float*)d_in[6];
  const float* vb        = (const float*)d_in[7];
  const float* cb        = (const float*)d_in[8];
  const float* Wg        = (const float*)d_in[9];
  const float* bg        = (const float*)d_in[10];
  const float* Wz        = (const float*)d_in[11];
  const float* Uz        = (const float*)d_in[12];
  const float* bz        = (const float*)d_in[13];
  const float* Wr        = (const float*)d_in[14];
  const float* Ur        = (const float*)d_in[15];
  const float* br        = (const float*)d_in[16];
  const float* Wh        = (const float*)d_in[17];
  const float* Uh        = (const float*)d_in[18];
  const float* bh        = (const float*)d_in[19];
  float* out = (float*)d_out;
  char* ws = (char*)d_ws;
  const size_t MB = (size_t)1 << 20;

  float* vfwd   = (float*)(ws + 0);        // 2 MB (later reused as ve2)
  float* dmat   = (float*)(ws + 2 * MB);   // 8 MB
  double* nvd   = (double*)(ws + 10 * MB); // 4 MB (f64 accumulator)
  u64* vbs      = (u64*)(ws + 16 * MB);    // 64 MB: [var][512][2] {mask, sign}
  float* zbuf   = (float*)(ws + 16 * MB);  // 2 MB (reuses dead vbs region)
  float* rpbuf  = (float*)(ws + 18 * MB);  // 2 MB
  bool fast = ws_size >= 80 * MB;

  k_varsfwd<<<512, 256, 0, stream>>>(variables, fb, vfwd);
  hipMemsetAsync(nvd, 0, (size_t)NVAR * 64 * sizeof(double), stream);
  if (fast) {
    k_pass1v2<<<1024, 512, 0, stream>>>(cpos, cneg, vfwd, fb + 4096, cb, dmat,
                                        (unsigned*)vbs);
    k_gather3<<<2048 * GSEG, 256, 0, stream>>>(vbs, dmat, nvd);
  } else {
    k_pass1_basic<<<8192, 256, 0, stream>>>(cpos, cneg, vfwd, fb + 4096, cb, dmat);
    k_pass2_dense<<<128 * CSEG, 256, 0, stream>>>(cpos, cneg, dmat, nvd);
  }
  k_tail1<<<256, 256, 0, stream>>>(nvd, vb, ground, Wg, bg, vfwd);
  k_tailg<0><<<256, 256, 0, stream>>>(vfwd, variables, Wz, Uz, bz, variables,
                                      nullptr, zbuf);
  k_tailg<1><<<256, 256, 0, stream>>>(vfwd, variables, Wr, Ur, br, variables,
                                      nullptr, rpbuf);
  k_tailg<2><<<256, 256, 0, stream>>>(vfwd, rpbuf, Wh, Uh, bh, variables, zbuf,
                                      out);
}

// Round 6
// 881.640 us; speedup vs baseline: 1.7723x; 1.3651x over previous
//
#include <hip/hip_runtime.h>
#include <stdint.h>

typedef unsigned long long u64;

#define NVAR 8192
#define NCLS 32768
#define CSEG 16
#define GSEG 4           // gather segments (128 chunks each)
#define LCAP 1152        // per-warp gather list capacity (mean 324 + 47 sigma)

__device__ __forceinline__ float lane_bc(float v, int l) { return __shfl(v, l); }

__device__ __forceinline__ u64 readfl64(u64 x) {
  unsigned lo = __builtin_amdgcn_readfirstlane((unsigned)x);
  unsigned hi = __builtin_amdgcn_readfirstlane((unsigned)(x >> 32));
  return ((u64)hi << 32) | (u64)lo;
}

__device__ __forceinline__ u64 shflx64(u64 x, int m) {
  unsigned lo = (unsigned)__shfl_xor((int)(unsigned)x, m, 64);
  unsigned hi = (unsigned)__shfl_xor((int)(unsigned)(x >> 32), m, 64);
  return ((u64)hi << 32) | (u64)lo;
}

// ---------------- kernel 1: vars_fwd = v @ fb0^T  [NVAR,64] ----------------
__global__ __launch_bounds__(256) void k_varsfwd(const float* __restrict__ v,
                                                 const float* __restrict__ fb0,
                                                 float* __restrict__ out) {
  __shared__ float fbt[64 * 64];   // fbt[k][d] = fb0[d][k]
  __shared__ float vrow[4][64];
  int t = threadIdx.x;
#pragma unroll
  for (int i = 0; i < 16; ++i) {
    int idx = i * 256 + t;                       // idx = d*64+k
    fbt[(idx & 63) * 64 + (idx >> 6)] = fb0[idx];
  }
  __syncthreads();
  int w = t >> 6, lane = t & 63;
  for (int rr = 0; rr < 16; rr += 4) {
    int row = blockIdx.x * 16 + rr + w;
    vrow[w][lane] = v[row * 64 + lane];
    __syncthreads();
    double a = 0.0;
#pragma unroll
    for (int k = 0; k < 64; ++k)
      a = fma((double)vrow[w][k], (double)fbt[k * 64 + lane], a);
    out[row * 64 + lane] = (float)a;
    __syncthreads();
  }
}

// ======================= FAST PATH =======================
// pass 1: block = 32 clauses. Reg-prefetched LDS staging of vfwd; butterfly
// bit-transpose (4 warps, 6 shfl_xor steps) emitting vbs[var][cc][h] u64
// = {lo32: presence over 32 clauses, hi32: sign}.
__global__ __launch_bounds__(512, 8) void k_pass1v3(
    const float* __restrict__ pos, const float* __restrict__ neg,
    const float* __restrict__ vfwd, const float* __restrict__ fb1,
    const float* __restrict__ cbias, float* __restrict__ dmat,
    u64* __restrict__ vbs) {
  __shared__ float sbuf[128 * 64];        // 32KB staging; epilogue: fbt+crow
  __shared__ u64 lm[2][32][4];            // double-buffered presence masks
  __shared__ u64 lsg[2][32][4];           // sign masks
  int t = threadIdx.x;
  int w = __builtin_amdgcn_readfirstlane(t >> 6);   // warp 0..7
  int lane = t & 63;
  int bx = blockIdx.x;             // 0..1023
  int c0 = bx * 32;                // first clause
  int cb = bx >> 1;                // 64-clause chunk
  int h = bx & 1;                  // which half (clauses cb*64+h*32..+32)
  double acc[4];
#pragma unroll
  for (int i = 0; i < 4; ++i) acc[i] = 0.0;

  for (int g = 0; g < 32; ++g) {   // 256-var groups
    int par = g & 1;
    // ---- ph1: issue h0 stage loads; stream pos/neg; ballots -> lm/lsg ----
    const float4* s0 = (const float4*)(vfwd + (size_t)g * 256 * 64);
    float4 st0 = s0[t], st1 = s0[t + 512], st2 = s0[t + 1024], st3 = s0[t + 1536];
#pragma unroll
    for (int i = 0; i < 4; i += 2) {
      size_t rb0 = (size_t)(c0 + w * 4 + i) * 2048 + (size_t)g * 64 + lane;
      size_t rb1 = rb0 + 2048;
      float4 p0 = ((const float4*)pos)[rb0];
      float4 q0 = ((const float4*)neg)[rb0];
      float4 p1 = ((const float4*)pos)[rb1];
      float4 q1 = ((const float4*)neg)[rb1];
      float a0[4], a1[4];
      a0[0] = p0.x - q0.x; a0[1] = p0.y - q0.y; a0[2] = p0.z - q0.z; a0[3] = p0.w - q0.w;
      a1[0] = p1.x - q1.x; a1[1] = p1.y - q1.y; a1[2] = p1.z - q1.z; a1[3] = p1.w - q1.w;
      int cl0 = w * 4 + i, cl1 = cl0 + 1;
#pragma unroll
      for (int j = 0; j < 4; ++j) {
        u64 m = __ballot(a0[j] != 0.f);
        u64 sg = __ballot(a0[j] < 0.f);
        if (lane == j) { lm[par][cl0][j] = m; lsg[par][cl0][j] = sg; }
      }
#pragma unroll
      for (int j = 0; j < 4; ++j) {
        u64 m = __ballot(a1[j] != 0.f);
        u64 sg = __ballot(a1[j] < 0.f);
        if (lane == j) { lm[par][cl1][j] = m; lsg[par][cl1][j] = sg; }
      }
    }
    __syncthreads();   // BAR1 (also drains h0 stage loads)

    // ---- ph2: write sbuf h0; warps 0-3 butterfly-transpose tile j=w ----
    {
      float4* dst = (float4*)sbuf;
      dst[t] = st0; dst[t + 512] = st1; dst[t + 1024] = st2; dst[t + 1536] = st3;
    }
    if (w < 4) {
      int jw = w;
      u64 A = (lane < 32) ? lm[par][lane][jw] : lsg[par][lane - 32][jw];
#define BSTEP(J, M)                                          \
      {                                                      \
        u64 B = shflx64(A, J);                               \
        u64 keep = (lane & J) ? ~(u64)(M) : (u64)(M);        \
        u64 B2 = (lane & J) ? (B >> J) : (B << J);           \
        A = (A & keep) | (B2 & ~keep);                       \
      }
      BSTEP(32, 0x00000000FFFFFFFFULL)
      BSTEP(16, 0x0000FFFF0000FFFFULL)
      BSTEP(8,  0x00FF00FF00FF00FFULL)
      BSTEP(4,  0x0F0F0F0F0F0F0F0FULL)
      BSTEP(2,  0x3333333333333333ULL)
      BSTEP(1,  0x5555555555555555ULL)
#undef BSTEP
      int v = (g << 8) + (lane << 2) + jw;
      vbs[((size_t)v * 512 + cb) * 2 + h] = A;   // {lo: mask32, hi: sign32}
    }
    __syncthreads();   // BAR2: h0 staged

    // ---- ph3: issue h1 stage loads; gather h0 (bits l<32) ----
    const float4* s1 = s0 + 2048;
    st0 = s1[t]; st1 = s1[t + 512]; st2 = s1[t + 1024]; st3 = s1[t + 1536];
#pragma unroll
    for (int i = 0; i < 4; ++i) {
      int cl = w * 4 + i;
#pragma unroll
      for (int j = 0; j < 4; ++j) {
        u64 m = readfl64(lm[par][cl][j]) & 0xffffffffULL;
        u64 sg = readfl64(lsg[par][cl][j]);
        while (m) {
          int l = __builtin_ctzll(m);
          m &= m - 1;
          float dv = sbuf[(l * 4 + j) * 64 + lane];
          acc[i] += ((sg >> l) & 1) ? -(double)dv : (double)dv;
        }
      }
    }
    __syncthreads();   // BAR3: gather0 done (drains h1 loads)

    // ---- ph4: write sbuf h1 ----
    {
      float4* dst = (float4*)sbuf;
      dst[t] = st0; dst[t + 512] = st1; dst[t + 1024] = st2; dst[t + 1536] = st3;
    }
    __syncthreads();   // BAR4: h1 staged

    // ---- ph5: gather h1 (bits l>=32); lm double-buffered -> no tail bar ----
#pragma unroll
    for (int i = 0; i < 4; ++i) {
      int cl = w * 4 + i;
#pragma unroll
      for (int j = 0; j < 4; ++j) {
        u64 m = readfl64(lm[par][cl][j]) >> 32;
        u64 sg = readfl64(lsg[par][cl][j]) >> 32;
        while (m) {
          int l = __builtin_ctzll(m);
          m &= m - 1;
          float dv = sbuf[(l * 4 + j) * 64 + lane];
          acc[i] += ((sg >> l) & 1) ? -(double)dv : (double)dv;
        }
      }
    }
  }
  __syncthreads();   // protect sbuf reuse in epilogue

  // ---- epilogue: relu + dmat = c @ fb1^T (sbuf reused: fbt + crow) ----
#pragma unroll
  for (int i2 = 0; i2 < 8; ++i2) {
    int idx = i2 * 512 + t;                      // idx = d*64+k
    sbuf[(idx & 63) * 64 + (idx >> 6)] = fb1[idx];
  }
  float* crow = sbuf + 4096 + w * 64;
  __syncthreads();
  for (int i = 0; i < 4; ++i) {
    float cv = fmaxf((float)acc[i] + cbias[lane], 0.f);
    crow[lane] = cv;
    __syncthreads();
    double da = 0.0;
#pragma unroll
    for (int k = 0; k < 64; ++k)
      da = fma((double)crow[k], (double)sbuf[k * 64 + lane], da);
    dmat[(size_t)(c0 + w * 4 + i) * 64 + lane] = (float)da;
    __syncthreads();
  }
}

// pass 2: decode masks -> LDS clause list, then 8-deep MLP gather.
// grid = GSEG * 2048 seg-major (2MB dmat slice per seg stays L2-resident).
__global__ __launch_bounds__(256, 8) void k_gather4(const u64* __restrict__ vbs,
                                                    const float* __restrict__ dmat,
                                                    double* __restrict__ nvd) {
  __shared__ unsigned short list[4][LCAP];
  int w = __builtin_amdgcn_readfirstlane(threadIdx.x >> 6);
  int lane = threadIdx.x & 63;
  int seg = blockIdx.x >> 11;              // 0..GSEG-1 (changes slowest)
  int v = (blockIdx.x & 2047) * 4 + w;
  int cc0 = seg * (512 / GSEG);
  // ---- decode: lane handles chunks cc0+2*lane, cc0+2*lane+1 ----
  const u64* P = vbs + ((size_t)v * 512 + cc0) * 2;
  u64 a0 = P[lane * 4 + 0], a1 = P[lane * 4 + 1];
  u64 b0 = P[lane * 4 + 2], b1 = P[lane * 4 + 3];
  u64 m0 = (a0 & 0xffffffffULL) | (a1 << 32);
  u64 s0 = (a0 >> 32) | (a1 & 0xffffffff00000000ULL);
  u64 m1 = (b0 & 0xffffffffULL) | (b1 << 32);
  u64 s1 = (b0 >> 32) | (b1 & 0xffffffff00000000ULL);
  int cnt = __popcll(m0) + __popcll(m1);
  int pre = cnt;
#pragma unroll
  for (int d = 1; d < 64; d <<= 1) {
    int o = __shfl_up(pre, d, 64);
    if (lane >= d) pre += o;
  }
  int tot = __shfl(pre, 63, 64);
  int base = pre - cnt;
#pragma unroll
  for (int half = 0; half < 2; ++half) {
    u64 m = half ? m1 : m0;
    u64 s = half ? s1 : s0;
    int cbase = (cc0 + 2 * lane + half) * 64;
    while (m) {
      int b = __builtin_ctzll(m);
      m &= m - 1;
      if (base < LCAP)
        list[w][base] = (unsigned short)((cbase + b) | (((s >> b) & 1) << 15));
      ++base;
    }
  }
  __syncthreads();
  if (tot > LCAP) tot = LCAP;
  // ---- gather: 8 independent dmat loads per iteration ----
  const u64* lp = (const u64*)&list[w][0];
  double acc = 0.0;
  int k = 0;
  for (; k + 8 <= tot; k += 8) {
    u64 L0 = lp[k >> 2], L1 = lp[(k >> 2) + 1];
    unsigned e[8];
#pragma unroll
    for (int q = 0; q < 4; ++q) {
      e[q] = (unsigned)(L0 >> (16 * q)) & 0xffffu;
      e[4 + q] = (unsigned)(L1 >> (16 * q)) & 0xffffu;
    }
    float dv[8];
#pragma unroll
    for (int q = 0; q < 8; ++q)
      dv[q] = dmat[(size_t)(e[q] & 0x7fffu) * 64 + lane];
#pragma unroll
    for (int q = 0; q < 8; ++q)
      acc += (e[q] & 0x8000u) ? -(double)dv[q] : (double)dv[q];
  }
  for (; k < tot; ++k) {
    unsigned e = list[w][k];
    float dv = dmat[(size_t)(e & 0x7fffu) * 64 + lane];
    acc += (e & 0x8000u) ? -(double)dv : (double)dv;
  }
  atomicAdd(&nvd[(size_t)v * 64 + lane], acc);
}

// ======================= FALLBACK PATH (ws too small) =======================
__global__ __launch_bounds__(256) void k_pass1_basic(
    const float* __restrict__ pos, const float* __restrict__ neg,
    const float* __restrict__ bmat, const float* __restrict__ fb1,
    const float* __restrict__ cbias, float* __restrict__ dmat) {
  __shared__ float fbt[64 * 64];
  __shared__ float crow[4][64];
  int t = threadIdx.x;
#pragma unroll
  for (int i = 0; i < 16; ++i) {
    int idx = i * 256 + t;
    fbt[(idx & 63) * 64 + (idx >> 6)] = fb1[idx];
  }
  __syncthreads();
  int w = t >> 6, lane = t & 63;
  int c = blockIdx.x * 4 + w;
  const float4* prow = (const float4*)(pos + (size_t)c * NVAR);
  const float4* nrow = (const float4*)(neg + (size_t)c * NVAR);
  double acc = 0.0;
  for (int g = 0; g < 32; ++g) {
    float4 p = prow[g * 64 + lane];
    float4 q = nrow[g * 64 + lane];
    float sc[4];
    sc[0] = p.x - q.x; sc[1] = p.y - q.y; sc[2] = p.z - q.z; sc[3] = p.w - q.w;
#pragma unroll
    for (int j = 0; j < 4; ++j) {
      float s = sc[j];
      u64 m = __ballot(s != 0.f);
      u64 sg = __ballot(s < 0.f);
      while (m) {
        int l = __builtin_ctzll(m);
        m &= m - 1;
        float dv = bmat[(size_t)((g << 8) + (l << 2) + j) * 64 + lane];
        acc += ((sg >> l) & 1) ? -(double)dv : (double)dv;
      }
    }
  }
  float cv = fmaxf((float)acc + cbias[lane], 0.f);
  crow[w][lane] = cv;
  __syncthreads();
  double da = 0.0;
#pragma unroll
  for (int k = 0; k < 64; ++k)
    da = fma((double)crow[w][k], (double)fbt[k * 64 + lane], da);
  dmat[(size_t)c * 64 + lane] = (float)da;
}

__global__ __launch_bounds__(256) void k_pass2_dense(
    const float* __restrict__ pos, const float* __restrict__ neg,
    const float* __restrict__ dmat, double* __restrict__ nvd) {
  __shared__ float acc[64 * 64];
  int t = threadIdx.x;
#pragma unroll
  for (int i = 0; i < 16; ++i) acc[i * 256 + t] = 0.f;
  __syncthreads();
  int w = t >> 6, lane = t & 63;
  int s = blockIdx.x / CSEG, seg = blockIdx.x % CSEG;
  int c0 = seg * (NCLS / CSEG);
  for (int c = c0 + w; c < c0 + NCLS / CSEG; c += 4) {
    float p = pos[(size_t)c * NVAR + (s << 6) + lane];
    float q = neg[(size_t)c * NVAR + (s << 6) + lane];
    float sv = p - q;
    u64 m = __ballot(sv != 0.f);
    if (!m) continue;
    float dv = dmat[(size_t)c * 64 + lane];
    while (m) {
      int l = __builtin_ctzll(m);
      m &= m - 1;
      float sl = lane_bc(sv, l);
      atomicAdd(&acc[(l << 6) + lane], sl * dv);
    }
  }
  __syncthreads();
  size_t obase = (size_t)s * 4096;
#pragma unroll
  for (int i = 0; i < 16; ++i) {
    int idx = i * 256 + t;
    atomicAdd(&nvd[obase + idx], (double)acc[idx]);
  }
}

// ------- fused tail: ve2 = tanh(cat(ground, relu(nvd+vb))@Wg^T+bg), then
//         full GRU (z, r, h, out) per row in one kernel. Per-wave pipeline,
//         no block barriers after the weight load.
__global__ __launch_bounds__(256, 1) void k_tailfused(
    const double* __restrict__ nvd, const float* __restrict__ vb,
    const float* __restrict__ ground, const float* __restrict__ Wg,
    const float* __restrict__ bg,
    const float* __restrict__ Wz, const float* __restrict__ Uz,
    const float* __restrict__ bz,
    const float* __restrict__ Wr, const float* __restrict__ Ur,
    const float* __restrict__ br,
    const float* __restrict__ Wh, const float* __restrict__ Uh,
    const float* __restrict__ bh,
    const float* __restrict__ prev, float* __restrict__ out) {
  __shared__ float wg[72 * 65];                    // wg[k][d], pad 65
  __shared__ float wz[64 * 65], uz[64 * 65], wr[64 * 65], ur[64 * 65],
      wh[64 * 65], uh[64 * 65];
  __shared__ float xrow[4][72], yrow[4][64], prow[4][64], rprow[4][64];
  int t = threadIdx.x;
#pragma unroll
  for (int i = 0; i < 18; ++i) {
    int idx = i * 256 + t;                         // d*72+k
    wg[(idx % 72) * 65 + (idx / 72)] = Wg[idx];
  }
#pragma unroll
  for (int i = 0; i < 16; ++i) {
    int idx = i * 256 + t;                         // d*64+k
    int a = (idx & 63) * 65 + (idx >> 6);
    wz[a] = Wz[idx]; uz[a] = Uz[idx]; wr[a] = Wr[idx];
    ur[a] = Ur[idx]; wh[a] = Wh[idx]; uh[a] = Uh[idx];
  }
  __syncthreads();
  int w = t >> 6, lane = t & 63;
  for (int rr = 0; rr < 8; ++rr) {
    int row = blockIdx.x * 32 + w * 8 + rr;
    float pv = prev[row * 64 + lane];
    float ve = fmaxf((float)nvd[row * 64 + lane] + vb[lane], 0.f);
    xrow[w][8 + lane] = ve;
    if (lane < 8) xrow[w][lane] = ground[row * 8 + lane];
    prow[w][lane] = pv;
    double a = 0.0;
#pragma unroll
    for (int k = 0; k < 72; ++k)
      a = fma((double)xrow[w][k], (double)wg[k * 65 + lane], a);
    float ve2 = tanhf((float)a + bg[lane]);
    yrow[w][lane] = ve2;
    float az = bz[lane], ar = br[lane];
#pragma unroll
    for (int k = 0; k < 64; ++k) {
      float y = yrow[w][k], p = prow[w][k];
      az = fmaf(y, wz[k * 65 + lane], az);
      az = fmaf(p, uz[k * 65 + lane], az);
      ar = fmaf(y, wr[k * 65 + lane], ar);
      ar = fmaf(p, ur[k * 65 + lane], ar);
    }
    float r = 1.f / (1.f + expf(-ar));
    rprow[w][lane] = r * pv;
    float ah = bh[lane];
#pragma unroll
    for (int k = 0; k < 64; ++k) {
      ah = fmaf(yrow[w][k], wh[k * 65 + lane], ah);
      ah = fmaf(rprow[w][k], uh[k * 65 + lane], ah);
    }
    float z = 1.f / (1.f + expf(-az));
    float hh = tanhf(ah);
    out[row * 64 + lane] = (1.f - z) * pv + z * hh;
  }
}

extern "C" void kernel_launch(void* const* d_in, const int* in_sizes, int n_in,
                              void* d_out, int out_size, void* d_ws, size_t ws_size,
                              hipStream_t stream) {
  const float* variables = (const float*)d_in[0];
  const float* ground    = (const float*)d_in[1];
  const float* cpos      = (const float*)d_in[2];
  const float* cneg      = (const float*)d_in[3];
  const float* fb        = (const float*)d_in[6];
  const float* vb        = (const float*)d_in[7];
  const float* cb        = (const float*)d_in[8];
  const float* Wg        = (const float*)d_in[9];
  const float* bg        = (const float*)d_in[10];
  const float* Wz        = (const float*)d_in[11];
  const float* Uz        = (const float*)d_in[12];
  const float* bz        = (const float*)d_in[13];
  const float* Wr        = (const float*)d_in[14];
  const float* Ur        = (const float*)d_in[15];
  const float* br        = (const float*)d_in[16];
  const float* Wh        = (const float*)d_in[17];
  const float* Uh        = (const float*)d_in[18];
  const float* bh        = (const float*)d_in[19];
  float* out = (float*)d_out;
  char* ws = (char*)d_ws;
  const size_t MB = (size_t)1 << 20;

  float* vfwd   = (float*)(ws + 0);        // 2 MB
  float* dmat   = (float*)(ws + 2 * MB);   // 8 MB
  double* nvd   = (double*)(ws + 10 * MB); // 4 MB (f64 accumulator)
  u64* vbs      = (u64*)(ws + 16 * MB);    // 64 MB: [var][512][2] {m32|s32<<32}
  bool fast = ws_size >= 80 * MB;

  k_varsfwd<<<512, 256, 0, stream>>>(variables, fb, vfwd);
  hipMemsetAsync(nvd, 0, (size_t)NVAR * 64 * sizeof(double), stream);
  if (fast) {
    k_pass1v3<<<1024, 512, 0, stream>>>(cpos, cneg, vfwd, fb + 4096, cb, dmat,
                                        vbs);
    k_gather4<<<2048 * GSEG, 256, 0, stream>>>(vbs, dmat, nvd);
  } else {
    k_pass1_basic<<<8192, 256, 0, stream>>>(cpos, cneg, vfwd, fb + 4096, cb, dmat);
    k_pass2_dense<<<128 * CSEG, 256, 0, stream>>>(cpos, cneg, dmat, nvd);
  }
  k_tailfused<<<256, 256, 0, stream>>>(nvd, vb, ground, Wg, bg, Wz, Uz, bz,
                                       Wr, Ur, br, Wh, Uh, bh, variables, out);
}